// Round 10
// baseline (3216.918 us; speedup 1.0000x reference)
//
#include <hip/hip_runtime.h>
#include <hip/hip_bf16.h>

#define NCLS 3
#define NPTS 64
#define NEDGE 2016   // 64*63/2
#define MIN_SAMP 200

__device__ int          g_counts[NCLS];
__device__ int          g_sel[NCLS][NPTS];
__device__ float        g_Dm[NCLS][NPTS * NPTS];
__device__ float        g_tp[NCLS];
__device__ int          g_ovf[NCLS];
__device__ unsigned int g_rows[NCLS][NEDGE][64];   // fallback-only state

__global__ void init_k() {
    if (threadIdx.x < NCLS) { g_counts[threadIdx.x] = 0; g_ovf[threadIdx.x] = 0; }
}

__global__ __launch_bounds__(256) void count_k(const int* __restrict__ labels, int N) {
    __shared__ int c3[NCLS];
    if (threadIdx.x < NCLS) c3[threadIdx.x] = 0;
    __syncthreads();
    for (int i = blockIdx.x * blockDim.x + threadIdx.x; i < N; i += gridDim.x * blockDim.x) {
        int c = labels[i];
        if ((unsigned)c < NCLS) atomicAdd(&c3[c], 1);
    }
    __syncthreads();
    if (threadIdx.x < NCLS) atomicAdd(&g_counts[threadIdx.x], c3[threadIdx.x]);
}

__global__ __launch_bounds__(64) void select_k(const int* __restrict__ labels, int N) {
    const int lane = threadIdx.x;
    int cnt[NCLS] = {0, 0, 0};
    for (int base = 0; base < N; base += 64) {
        if (cnt[0] >= NPTS && cnt[1] >= NPTS && cnt[2] >= NPTS) break;
        int lab = (base + lane < N) ? labels[base + lane] : -1;
        for (int c = 0; c < NCLS; ++c) {
            if (cnt[c] >= NPTS) continue;
            unsigned long long m = __ballot(lab == c);
            if (!m) continue;
            int pos = cnt[c] + __popcll(m & ((1ull << lane) - 1ull));
            if (lab == c && pos < NPTS) g_sel[c][pos] = base + lane;
            cnt[c] = min(NPTS, cnt[c] + (int)__popcll(m));
        }
    }
}

__global__ __launch_bounds__(256) void dist_k(const float* __restrict__ feat) {
    int cls = blockIdx.x;
    if (g_counts[cls] < MIN_SAMP) return;
    int p = blockIdx.y * 256 + threadIdx.x;
    int i = p >> 6, j = p & 63;
    const float4* pi = (const float4*)(feat + (size_t)g_sel[cls][i] * 768);
    const float4* pj = (const float4*)(feat + (size_t)g_sel[cls][j] * 768);
    float sq = 0.f;
    #pragma unroll 4
    for (int d = 0; d < 192; ++d) {
        float4 va = pi[d], vb = pj[d];
        float dx = va.x - vb.x, dy = va.y - vb.y, dz = va.z - vb.z, dw = va.w - vb.w;
        sq = fmaf(dx, dx, sq); sq = fmaf(dy, dy, sq);
        sq = fmaf(dz, dz, sq); sq = fmaf(dw, dw, sq);
    }
    g_Dm[cls][p] = sqrtf(fmaxf(sq, 1e-12f));
}

__device__ __forceinline__ uint4 shfl4(uint4 v, int src) {
    uint4 r;
    r.x = (unsigned)__shfl((int)v.x, src);
    r.y = (unsigned)__shfl((int)v.y, src);
    r.z = (unsigned)__shfl((int)v.z, src);
    r.w = (unsigned)__shfl((int)v.w, src);
    return r;
}
__device__ __forceinline__ void xor4(uint4& a, const uint4 b) {
    a.x ^= b.x; a.y ^= b.y; a.z ^= b.z; a.w ^= b.w;
}
__device__ __forceinline__ unsigned int getw4(const uint4 a, int m) {
    return (m < 32) ? a.x : (m < 64) ? a.y : (m < 96) ? a.z : a.w;
}
__device__ __forceinline__ void set4(uint4& a, int m) {
    const unsigned int b = 1u << (m & 31);
    if (m < 32) a.x |= b; else if (m < 64) a.y |= b; else if (m < 96) a.z |= b; else a.w |= b;
}
__device__ __forceinline__ bool any4(const uint4 a, const uint4 b) {
    return ((a.x & b.x) | (a.y & b.y) | (a.z & b.z) | (a.w & b.w)) != 0u;
}

// Serial-chain apply, pivot-indexed: 1 LDS load per pending bit.
// Mutual-reduction invariant => application set w = v & pm fixed up front.
__device__ __forceinline__ uint4 pend_apply(uint4 v, const uint4 pm, const uint4* pend) {
    unsigned int w;
    w = v.x & pm.x;
    while (w) { int c = __builtin_ctz(w); w &= w - 1; xor4(v, pend[c]); }
    w = v.y & pm.y;
    while (w) { int c = __builtin_ctz(w); w &= w - 1; xor4(v, pend[32 + c]); }
    w = v.z & pm.z;
    while (w) { int c = __builtin_ctz(w); w &= w - 1; xor4(v, pend[64 + c]); }
    w = v.w & pm.w;
    while (w) { int c = __builtin_ctz(w); w &= w - 1; xor4(v, pend[96 + c]); }
    return v;
}

// ---------------- fast path: annotation H1 persistence, lazy pivot-indexed pending ----------------
// 16 waves rank edges; wave 0 runs the filtration with one-group-ahead prefetch of
// all static-table and annotation LDS reads (se/ev/rank2d/M) so the per-group
// critical path holds only: event shfls, pend_apply, Gauss-Jordan, append.
__global__ __launch_bounds__(1024) void persist_fast_k() {
    const int cls  = blockIdx.x;
    const int tid  = threadIdx.x;
    const int lane = tid & 63;
    const int wid  = tid >> 6;
    if (g_counts[cls] < MIN_SAMP) return;

    __shared__ union UA {
        float sDm[NPTS * NPTS];          // ranking phase (16 KB)
        uint4 M[NEDGE];                  // edge annotations (32.25 KB)
    } uA;
    __shared__ short         rank2d[NPTS * NPTS];       // 8 KB
    __shared__ unsigned char se_i[NEDGE], se_j[NEDGE];  // 4 KB
    __shared__ float         ev[NEDGE];                 // 8 KB
    __shared__ unsigned char e2i[NEDGE], e2j[NEDGE];    // 4 KB (ranking only)
    __shared__ uint4         s_pend[128];               // 2 KB, indexed by pivot slot
    __shared__ unsigned char s_plist[128];              // pending pivot list (group-ordered)

    for (int p = tid; p < NPTS * NPTS; p += 1024) uA.sDm[p] = g_Dm[cls][p];
    if (tid < NPTS - 1) {
        int i = tid;
        int base = i * (2 * NPTS - 1 - i) / 2;
        for (int j = i + 1; j < NPTS; ++j) {
            e2i[base + j - i - 1] = (unsigned char)i;
            e2j[base + j - i - 1] = (unsigned char)j;
        }
    }
    if (tid < NPTS) rank2d[tid * NPTS + tid] = 0x7fff;   // diagonal guard
    __syncthreads();

    // Rank edges by (value, i, j) — matches reference lexsort((jj,ii,vals)).
    for (int e = tid; e < NEDGE; e += 1024) {
        int i_ = e2i[e], j_ = e2j[e];
        float v = uA.sDm[i_ * NPTS + j_];
        int rk = 0;
        for (int f = 0; f < NEDGE; ++f) {
            int fi = e2i[f], fj = e2j[f];
            float w = uA.sDm[fi * NPTS + fj];
            bool less = (w < v) || (w == v && (fi < i_ || (fi == i_ && fj < j_)));
            rk += less ? 1 : 0;
        }
        se_i[rk] = (unsigned char)i_;
        se_j[rk] = (unsigned char)j_;
        ev[rk]   = v;
        rank2d[i_ * NPTS + j_] = (short)rk;
        rank2d[j_ * NPTS + i_] = (short)rk;
    }
    __syncthreads();          // ranking done; sDm dead, M takes over (no init needed)

    if (wid != 0) return;     // ---- single-wave main loop ----

    int   rootv = lane;                               // DSU root of vertex==lane
    uint4 pi    = make_uint4(0u, 0u, 0u, 0u);         // vertex potential (stale basis)
    uint4 occ      = make_uint4(0u, 0u, 0u, 0u);      // live + dead-pending slots
    uint4 pendmask = make_uint4(0u, 0u, 0u, 0u);
    int   pcount = 0, inuse = 0, plc = 0, bail = 0;
    double birth = 0.0, death = 0.0;

    // Prefetch bundle for group 0 (no valid candidates at r=0).
    int   pf_i = se_i[0], pf_j = se_j[0];
    float pf_e = ev[0];
    short pf_a = rank2d[pf_i * NPTS + lane];
    short pf_b = rank2d[pf_j * NPTS + lane];
    bool  pf_v = false;
    uint4 pf_Ma = make_uint4(0u, 0u, 0u, 0u), pf_Mb = pf_Ma;

    for (int r = 0; r < NEDGE; ++r) {
        // ---- consume prefetch ----
        const int   i_  = pf_i, j_ = pf_j;
        const float evr = pf_e;
        const short a_l = pf_a, b_l = pf_b;
        const bool  validk = pf_v;
        uint4 Ma = pf_Ma, Mb = pf_Mb;

        // ---- flush when slot pressure high (dead slots stay in occ until flush) ----
        if (inuse >= 126) {
            for (int x = lane; x < r; x += 64) {
                uint4 row = uA.M[x];
                if (any4(row, pendmask)) uA.M[x] = pend_apply(row, pendmask, s_pend);
            }
            pi = pend_apply(pi, pendmask, s_pend);
            occ.x &= ~pendmask.x; occ.y &= ~pendmask.y;
            occ.z &= ~pendmask.z; occ.w &= ~pendmask.w;
            inuse -= pcount; pcount = 0; plc = 0;
            pendmask = make_uint4(0u, 0u, 0u, 0u);
            if (inuse >= 126) { bail = 1; break; }    // genuine beta_1 overflow
            // prefetched M rows predate the flush -> reload (now current-basis, pm=0)
            Ma = uA.M[validk ? (int)a_l : 0];
            Mb = uA.M[validk ? (int)b_l : 0];
        }

        // ---- edge event, uniform & registerized ----
        const int rootI = __shfl(rootv, i_);
        const int rootJ = __shfl(rootv, j_);
        uint4 ann = shfl4(pi, i_);
        xor4(ann, shfl4(pi, j_));
        if (rootI != rootJ) {
            rootv = (rootv == rootI) ? rootJ : rootv;    // negative edge: merge
        } else {
            birth += (double)evr;                        // positive edge: new class
            int s = (~occ.x) ? __builtin_ctz(~occ.x)
                  : (~occ.y) ? 32 + __builtin_ctz(~occ.y)
                  : (~occ.z) ? 64 + __builtin_ctz(~occ.z)
                  : (~occ.w) ? 96 + __builtin_ctz(~occ.w) : -1;
            if (s < 0) { bail = 1; break; }
            set4(occ, s); ++inuse;
            set4(ann, s);
        }
        if (lane == 0) uA.M[r] = ann;                    // stale-basis row; ann reused below

        // ---- prefetch bundle for group r+1 (after M[r] write: a_n/b_n may equal r) ----
        {
            const int rn = (r + 1 < NEDGE) ? r + 1 : r;
            pf_i = se_i[rn]; pf_j = se_j[rn];
            pf_e = ev[rn];
            pf_a = rank2d[pf_i * NPTS + lane];
            pf_b = rank2d[pf_j * NPTS + lane];
            pf_v = (lane != pf_i) && (lane != pf_j) && (pf_a < rn) && (pf_b < rn);
            pf_Ma = uA.M[pf_v ? (int)pf_a : 0];
            pf_Mb = uA.M[pf_v ? (int)pf_b : 0];
        }

        if (!__ballot(validk)) continue;

        // ---- candidate triangle tests (current basis via lazy apply) ----
        uint4 v = make_uint4(0u, 0u, 0u, 0u);
        if (validk) {
            v = Ma;
            xor4(v, Mb);
            xor4(v, ann);
            v = pend_apply(v, pendmask, s_pend);
        }

        // ---- wave-synchronous Gauss-Jordan over valid lanes ----
        uint4 s4 = make_uint4(0u, 0u, 0u, 0u);
        int accidx = -1, accm = 0;
        int d = 0;
        while (true) {
            unsigned long long nzm = __ballot((v.x | v.y | v.z | v.w) != 0u);
            if (!nzm) break;
            const int l = __builtin_ctzll(nzm);
            const uint4 p = shfl4(v, l);
            const int m = p.x ? __builtin_ctz(p.x) : p.y ? 32 + __builtin_ctz(p.y)
                       : p.z ? 64 + __builtin_ctz(p.z) : 96 + __builtin_ctz(p.w);
            if (lane == l) { s4 = v; accidx = d; accm = m; }
            const unsigned int mb2 = 1u << (m & 31);
            if (getw4(v, m) & mb2) xor4(v, p);
            if (accidx >= 0 && accidx < d) {
                if (getw4(s4, m) & mb2) xor4(s4, p);
            }
            ++d;
        }
        if (d == 0) continue;
        death += (double)d * (double)evr;

        // ---- append: parallel acceptor writes; npm via short shfl loop ----
        if (accidx >= 0) {
            s_pend[accm] = s4;                            // pivot-indexed, unique
            s_plist[plc + accidx] = (unsigned char)accm;  // group-ordered list
        }
        uint4 npm = make_uint4(0u, 0u, 0u, 0u);
        for (int t = 0; t < d; ++t) {
            const unsigned long long who = __ballot(accidx == t);
            const int l = __builtin_ctzll(who);
            const int m = __shfl(accm, l);
            set4(npm, m);
        }
        // old-entry fixup vs new pivots (maintain mutual reduction)
        for (int x = lane; x < plc; x += 64) {
            const int p = s_plist[x];
            uint4 q = s_pend[p];
            if (any4(q, npm)) s_pend[p] = pend_apply(q, npm, s_pend);
        }
        plc += d; pcount += d;
        pendmask.x |= npm.x; pendmask.y |= npm.y;
        pendmask.z |= npm.z; pendmask.w |= npm.w;
    }

    if (lane == 0) {
        if (bail) g_ovf[cls] = 1;
        else      g_tp[cls] = (float)(death - birth);
    }
}

// ---------------- fallback: R3's validated exact Row-matrix reduction ----------------
__global__ __launch_bounds__(1024) void persist_exact_k() {
    const int cls  = blockIdx.x;
    const int tid  = threadIdx.x;
    const int lane = tid & 63;
    const int wid  = tid >> 6;
    if (g_counts[cls] < MIN_SAMP) return;
    if (!g_ovf[cls]) return;

    union PhaseU {
        float        sDm[NPTS * NPTS];
        unsigned int pbuf[62][64];
    };
    __shared__ PhaseU        u;
    __shared__ short         rank2d[NPTS * NPTS];
    __shared__ unsigned char e2i[NEDGE], e2j[NEDGE];
    __shared__ unsigned char se_i[NEDGE], se_j[NEDGE];
    __shared__ float         ev[NEDGE];
    __shared__ unsigned char cstate[64];
    __shared__ int           s_t;
    __shared__ double        s_birth, s_death;
    __shared__ unsigned char parent[NPTS];

    for (int p = tid; p < NPTS * NPTS; p += 1024) u.sDm[p] = g_Dm[cls][p];
    if (tid < NPTS - 1) {
        int i = tid;
        int base = i * (2 * NPTS - 1 - i) / 2;
        for (int j = i + 1; j < NPTS; ++j) {
            e2i[base + j - i - 1] = (unsigned char)i;
            e2j[base + j - i - 1] = (unsigned char)j;
        }
    }
    for (int x = tid; x < NEDGE * 64; x += 1024) {
        int rr = x >> 6, w = x & 63;
        g_rows[cls][rr][w] = (w == (rr >> 5)) ? (1u << (rr & 31)) : 0u;
    }
    if (tid < NPTS) rank2d[tid * NPTS + tid] = 0x7fff;
    __syncthreads();

    for (int e = tid; e < NEDGE; e += 1024) {
        int i_ = e2i[e], j_ = e2j[e];
        float v = u.sDm[i_ * NPTS + j_];
        int rk = 0;
        for (int f = 0; f < NEDGE; ++f) {
            int fi = e2i[f], fj = e2j[f];
            float w = u.sDm[fi * NPTS + fj];
            bool less = (w < v) || (w == v && (fi < i_ || (fi == i_ && fj < j_)));
            rk += less ? 1 : 0;
        }
        se_i[rk] = (unsigned char)i_;
        se_j[rk] = (unsigned char)j_;
        ev[rk]   = v;
        rank2d[i_ * NPTS + j_] = (short)rk;
        rank2d[j_ * NPTS + i_] = (short)rk;
    }
    __syncthreads();

    if (tid == 0) {
        for (int i = 0; i < NPTS; ++i) parent[i] = (unsigned char)i;
        double bs = 0.0;
        for (int r = 0; r < NEDGE; ++r) {
            int x = se_i[r]; while (parent[x] != x) { parent[x] = parent[parent[x]]; x = parent[x]; }
            int y = se_j[r]; while (parent[y] != y) { parent[y] = parent[parent[y]]; y = parent[y]; }
            if (x == y) bs += (double)ev[r];
            else parent[x] = (unsigned char)y;
        }
        s_birth = bs; s_death = 0.0;
    }
    __syncthreads();

    unsigned int (*Row)[64] = g_rows[cls];

    for (int r = 1; r < NEDGE; ++r) {
        const int i_ = se_i[r], j_ = se_j[r];
        const int a_l = rank2d[i_ * NPTS + lane];
        const int b_l = rank2d[j_ * NPTS + lane];
        const bool valid = (lane != i_) && (lane != j_) && (a_l < r) && (b_l < r);
        const unsigned long long mask = __ballot(valid);
        if (!mask) continue;
        const int cnt = __popcll(mask);

        {
            const unsigned int rrow = Row[r][lane];
            for (int idx = wid; idx < cnt; idx += 16) {
                unsigned long long mm = mask;
                for (int s = 0; s < idx; ++s) mm &= mm - 1;
                const int k = __builtin_ctzll(mm);
                const int a = __shfl(a_l, k);
                const int b = __shfl(b_l, k);
                const unsigned int p = Row[a][lane] ^ Row[b][lane] ^ rrow;
                u.pbuf[idx][lane] = p;
                const bool indep = (__ballot(p != 0u) != 0ull);
                if (lane == 0) cstate[idx] = indep ? 1 : 0;
            }
        }
        __syncthreads();

        while (true) {
            int c = -1;
            for (int x = 0; x < cnt; ++x) if (cstate[x] == 1) { c = x; break; }
            if (c < 0) break;
            __syncthreads();
            if (wid == 0) {
                const unsigned int pw = u.pbuf[c][lane];
                const unsigned long long m2 = __ballot(pw != 0u);
                const int fl = __builtin_ctzll(m2);
                const unsigned int w0 = (unsigned int)__shfl((int)pw, fl);
                if (lane == 0) s_t = fl * 32 + __builtin_ctz(w0);
            }
            if (tid == 0) { s_death += (double)ev[r]; cstate[c] = 2; }
            __syncthreads();
            const int t = s_t, tw = t >> 5;
            const unsigned int tb = 1u << (t & 31);
            const unsigned int pw = u.pbuf[c][lane];
            for (int rr0 = wid * 64; rr0 < NEDGE; rr0 += 1024) {
                const int rr = rr0 + lane;
                unsigned int hit = (rr < NEDGE) ? (Row[rr][tw] & tb) : 0u;
                unsigned long long mrows = __ballot(hit != 0u);
                while (mrows) {
                    const int rx = rr0 + __builtin_ctzll(mrows);
                    mrows &= mrows - 1;
                    Row[rx][lane] ^= pw;
                }
            }
            __threadfence_block();
            __syncthreads();
            {
                const unsigned int rrow2 = Row[r][lane];
                for (int idx = wid; idx < cnt; idx += 16) {
                    if (cstate[idx] != 1) continue;
                    unsigned long long mm = mask;
                    for (int s = 0; s < idx; ++s) mm &= mm - 1;
                    const int k = __builtin_ctzll(mm);
                    const int a = __shfl(a_l, k);
                    const int b = __shfl(b_l, k);
                    const unsigned int p2 = Row[a][lane] ^ Row[b][lane] ^ rrow2;
                    u.pbuf[idx][lane] = p2;
                    const bool indep = (__ballot(p2 != 0u) != 0ull);
                    if (lane == 0) cstate[idx] = indep ? 1 : 0;
                }
            }
            __syncthreads();
        }
        __syncthreads();
    }

    if (tid == 0) g_tp[cls] = (float)(s_death - s_birth);
}

__global__ void final_k(const float* __restrict__ tgt, float* __restrict__ out) {
    double total = 0.0;
    int valid = 0;
    for (int c = 0; c < NCLS; ++c) {
        if (g_counts[c] >= MIN_SAMP) {
            double tpt = 0.0;
            for (int p = 0; p < 100; ++p)
                tpt += (double)tgt[(c * 100 + p) * 2 + 1] - (double)tgt[(c * 100 + p) * 2 + 0];
            double d = (double)g_tp[c] - tpt;
            total += d * d;
            valid++;
        }
    }
    *out = valid ? (float)(total / valid) : 0.0f;
}

extern "C" void kernel_launch(void* const* d_in, const int* in_sizes, int n_in,
                              void* d_out, int out_size, void* d_ws, size_t ws_size,
                              hipStream_t stream) {
    const float* feat   = (const float*)d_in[0];
    const int*   labels = (const int*)d_in[1];
    const float* tgt    = (const float*)d_in[2];
    const int N = in_sizes[1];

    hipLaunchKernelGGL(init_k,         dim3(1),        dim3(64),   0, stream);
    hipLaunchKernelGGL(count_k,        dim3(256),      dim3(256),  0, stream, labels, N);
    hipLaunchKernelGGL(select_k,       dim3(1),        dim3(64),   0, stream, labels, N);
    hipLaunchKernelGGL(dist_k,         dim3(NCLS, 16), dim3(256),  0, stream, feat);
    hipLaunchKernelGGL(persist_fast_k, dim3(NCLS),     dim3(1024), 0, stream);
    hipLaunchKernelGGL(persist_exact_k,dim3(NCLS),     dim3(1024), 0, stream);
    hipLaunchKernelGGL(final_k,        dim3(1),        dim3(1),    0, stream, tgt, (float*)d_out);
}